// Round 13
// baseline (343.234 us; speedup 1.0000x reference)
//
#include <hip/hip_runtime.h>
#include <hip/hip_bf16.h>
#include <stdint.h>

typedef unsigned short u16;
typedef short bf16x8 __attribute__((ext_vector_type(8)));
typedef float f32x4 __attribute__((ext_vector_type(4)));
typedef uint32_t u32x4 __attribute__((ext_vector_type(4)));

#define DEV __device__ __forceinline__

DEV u16 f2bf(float f) {            // RNE (exact, for hi/lo splits)
  union { float f; uint32_t u; } v; v.f = f;
  uint32_t u = v.u;
  return (u16)((u + 0x7FFFu + ((u >> 16) & 1u)) >> 16);
}
DEV float bf2f(u16 h) {
  union { uint32_t u; float f; } v; v.u = ((uint32_t)h) << 16;
  return v.f;
}
DEV uint32_t cvtpk_bf16(float lo, float hi) {   // dst[15:0]=bf(lo), dst[31:16]=bf(hi)
  uint32_t r;
  asm volatile("v_cvt_pk_bf16_f32 %0, %1, %2" : "=v"(r) : "v"(lo), "v"(hi));
  return r;
}

#if __has_builtin(__builtin_amdgcn_exp2f)
#define EXP2F(x) __builtin_amdgcn_exp2f(x)
#else
#define EXP2F(x) exp2f(x)
#endif

#define GLL(gp, lp) __builtin_amdgcn_global_load_lds(\
    (const __attribute__((address_space(1))) unsigned int*)(gp), \
    (__attribute__((address_space(3))) unsigned int*)(lp), 16, 0, 0)

// ---------------- merged prep kernel ----------------
__global__ void prep(const float* __restrict__ x,
                     const float* __restrict__ wq, const float* __restrict__ wk,
                     const float* __restrict__ wv, const float* __restrict__ wo,
                     u16* __restrict__ xh, u16* __restrict__ xl,
                     u16* __restrict__ wqkh, u16* __restrict__ wqkl,
                     u16* __restrict__ wvb, u16* __restrict__ wob) {
  const int blk = blockIdx.x;
  if (blk < 8192) {
    int i = blk * 256 + threadIdx.x;
    float4 v = ((const float4*)x)[i];
    ushort4 h, lo;
    h.x = f2bf(v.x); h.y = f2bf(v.y); h.z = f2bf(v.z); h.w = f2bf(v.w);
    lo.x = f2bf(v.x - bf2f(h.x)); lo.y = f2bf(v.y - bf2f(h.y));
    lo.z = f2bf(v.z - bf2f(h.z)); lo.w = f2bf(v.w - bf2f(h.w));
    ((ushort4*)xh)[i] = h;
    ((ushort4*)xl)[i] = lo;
  } else {
    int i = (blk - 8192) * 256 + threadIdx.x;
    int seg = i >> 18;
    int j = i & ((1 << 18) - 1);
    const float* src = (seg == 0) ? wq : (seg == 1) ? wk : (seg == 2) ? wv : wo;
    float4 v = ((const float4*)src)[j];
    ushort4 h;
    h.x = f2bf(v.x); h.y = f2bf(v.y); h.z = f2bf(v.z); h.w = f2bf(v.w);
    if (seg < 2) {
      ushort4 lo;
      lo.x = f2bf(v.x - bf2f(h.x)); lo.y = f2bf(v.y - bf2f(h.y));
      lo.z = f2bf(v.z - bf2f(h.z)); lo.w = f2bf(v.w - bf2f(h.w));
      ((ushort4*)wqkh)[i] = h;
      ((ushort4*)wqkl)[i] = lo;
    } else if (seg == 2) {
      ((ushort4*)wvb)[j] = h;
    } else {
      ((ushort4*)wob)[j] = h;
    }
  }
}

// ---------------- fused QKV projection GEMM (128x256 tile, 64x128/wave) ----------------
// Wave tile widened 64x64 -> 64x128: -25% LDS-read bytes per FLOP (kernel was
// LDS-throughput-bound). acc[4][8] = 128 VGPR; launch_bounds(256,2) caps 256.
// LDS 48 KB (A h/l 16K + B h/l 32K) -> 2 blocks/CU. 2-barrier structure (r11).
// V-blocks (bx>=8) write V^T directly via 4 col-chunk transposes in Bl scratch.
__global__ __launch_bounds__(256, 2) void qkv_gemm(
    const u16* __restrict__ xh, const u16* __restrict__ xl,
    const u16* __restrict__ wh, const u16* __restrict__ wl,
    const u16* __restrict__ wv,
    u16* __restrict__ qkh, u16* __restrict__ qkl, u16* __restrict__ vt) {
  __shared__ u16 Ah[4096], Al[4096], Bh[8192], Bl[8192];   // 48 KB
  const int t = threadIdx.x, w = t >> 6, l = t & 63, g = l >> 4, lr = l & 15;
  const int m0 = blockIdx.y * 128, n0 = blockIdx.x * 256;
  const bool split = (n0 < 2048);
  const u16* bsrc_h = split ? (wh + (size_t)n0 * 1024) : (wv + (size_t)(n0 - 2048) * 1024);
  const u16* bsrc_l = split ? (wl + (size_t)n0 * 1024) : wl;
  const int wr = w >> 1, wc = w & 1;      // 2x2 wave grid: wr = A 64-row half, wc = B 128-col half
  const int sk = (lr ^ (lr >> 2)) & 3;    // read-side swizzle key

  f32x4 zero = {0.f, 0.f, 0.f, 0.f};
  f32x4 acc[4][8];
#pragma unroll
  for (int mi = 0; mi < 4; ++mi)
#pragma unroll
    for (int ni = 0; ni < 8; ++ni) acc[mi][ni] = zero;

  for (int k0 = 0; k0 < 1024; k0 += 32) {
    __syncthreads();
    // stage A (128x32 h/l): 2 rounds each
#pragma unroll
    for (int i = 0; i < 2; ++i) {
      const int c = i * 256 + t;
      const int row = c >> 2;
      const int kc8 = ((c & 3) ^ (((c >> 2) ^ (c >> 4)) & 3)) * 8;
      const size_t goff = (size_t)(m0 + row) * 1024 + k0 + kc8;
      const int lo = i * 4096 + w * 1024;
      GLL(xh + goff, (char*)Ah + lo);
      if (split) GLL(xl + goff, (char*)Al + lo);
    }
    // stage B (256x32 h/l): 4 rounds each
#pragma unroll
    for (int i = 0; i < 4; ++i) {
      const int c = i * 256 + t;
      const int row = c >> 2;
      const int kc8 = ((c & 3) ^ (((c >> 2) ^ (c >> 4)) & 3)) * 8;
      const size_t goff = (size_t)row * 1024 + k0 + kc8;
      const int lo = i * 4096 + w * 1024;
      GLL(bsrc_h + goff, (char*)Bh + lo);
      if (split) GLL(bsrc_l + goff, (char*)Bl + lo);
    }
    __syncthreads();

    bf16x8 ah[4], al[4];
#pragma unroll
    for (int mi = 0; mi < 4; ++mi) {
      const int idx = (wr * 64 + mi * 16 + lr) * 32 + ((g ^ sk) << 3);
      ah[mi] = *(const bf16x8*)&Ah[idx];
      if (split) al[mi] = *(const bf16x8*)&Al[idx];
    }
#pragma unroll
    for (int ni = 0; ni < 8; ++ni) {
      const int idx = (wc * 128 + ni * 16 + lr) * 32 + ((g ^ sk) << 3);
      bf16x8 bh = *(const bf16x8*)&Bh[idx];
      bf16x8 bl;
      if (split) bl = *(const bf16x8*)&Bl[idx];
#pragma unroll
      for (int mi = 0; mi < 4; ++mi) {
        acc[mi][ni] = __builtin_amdgcn_mfma_f32_16x16x32_bf16(ah[mi], bh, acc[mi][ni], 0, 0, 0);
        if (split) {
          acc[mi][ni] = __builtin_amdgcn_mfma_f32_16x16x32_bf16(al[mi], bh, acc[mi][ni], 0, 0, 0);
          acc[mi][ni] = __builtin_amdgcn_mfma_f32_16x16x32_bf16(ah[mi], bl, acc[mi][ni], 0, 0, 0);
        }
      }
    }
  }

  if (split) {
#pragma unroll
    for (int mi = 0; mi < 4; ++mi)
#pragma unroll
      for (int ni = 0; ni < 8; ++ni)
#pragma unroll
        for (int r = 0; r < 4; ++r) {
          const int row = m0 + wr * 64 + mi * 16 + g * 4 + r;
          const int col = wc * 128 + ni * 16 + lr;
          const float cval = acc[mi][ni][r];
          const u16 h = f2bf(cval);
          qkh[(size_t)row * 2048 + n0 + col] = h;
          qkl[(size_t)row * 2048 + n0 + col] = f2bf(cval - bf2f(h));
        }
  } else {
    // V-transpose epilogue: 4 chunks of 64 cols through 16 KB scratch T = Bl
    // T[c][s]: elem addr c*128 + (s ^ sw(c)), sw(c) = (c&31)<<2
    const int n0v = n0 - 2048;
    u16* T = Bl;
    for (int cc = 0; cc < 4; ++cc) {
      if (wc == (cc >> 1)) {
#pragma unroll
        for (int mi = 0; mi < 4; ++mi)
#pragma unroll
          for (int nj = 0; nj < 4; ++nj) {
            const int ni = (cc & 1) * 4 + nj;
            const int c = nj * 16 + lr;
            const int row0 = wr * 64 + mi * 16 + g * 4;
            const int sw = (c & 31) << 2;
            uint2 pk;
            pk.x = cvtpk_bf16(acc[mi][ni][0], acc[mi][ni][1]);
            pk.y = cvtpk_bf16(acc[mi][ni][2], acc[mi][ni][3]);
            *(uint2*)&T[c * 128 + (row0 ^ sw)] = pk;
          }
      }
      __syncthreads();
      {
        const int cb = t >> 4;       // 0..15
        const int sl = t & 15;       // 0..15
#pragma unroll
        for (int e = 0; e < 4; ++e) {
          const int c = cb + e * 16; // 0..63
          const int sw = (c & 31) << 2;
          const int s = sl * 8;      // 0..120
          const int p0 = s ^ sw;
          const int p1 = p0 ^ 4;
          uint2 lo = *(const uint2*)&T[c * 128 + p0];
          uint2 hi = *(const uint2*)&T[c * 128 + p1];
          uint4 ov; ov.x = lo.x; ov.y = lo.y; ov.z = hi.x; ov.w = hi.y;
          *(uint4*)&vt[(size_t)(n0v + cc * 64 + c) * 8192 + m0 + s] = ov;
        }
      }
      __syncthreads();
    }
  }
}

// ---------------- flash attention with ALiBi (8 waves x 32q, 256 q/block) ----------------
// Frozen round-9/12 state: permuted K staging, zero-shuffle in-reg P, swapped PV,
// lane-local softmax, wave-group stagger, triple-buffered K/V LDS.
__global__ __launch_bounds__(512, 2) void attn(
    const u16* __restrict__ qkh, const u16* __restrict__ qkl,
    const u16* __restrict__ vt, u16* __restrict__ multi) {
  __shared__ u16 Ksh[3][4096], Ksl[3][4096], Vts[3][4096];
  const int t = threadIdx.x, w = t >> 6, l = t & 63, g = l >> 4, lr = l & 15;
  // XCD-chunked bijective swizzle
  const int L = blockIdx.x;
  const int flat = (L & 7) * 64 + (L >> 3);
  const int b = flat >> 7, h = (flat >> 3) & 15, qt = flat & 7;
  const int q0 = qt * 256;
  const size_t rowbase = (size_t)b * 2048;
  const u16* Qh = qkh + rowbase * 2048 + h * 64;
  const u16* Ql = qkl + rowbase * 2048 + h * 64;
  const u16* Kh = qkh + rowbase * 2048 + 1024 + h * 64;
  const u16* Kl = qkl + rowbase * 2048 + 1024 + h * 64;
  const u16* Vb = vt + (size_t)(h * 64) * 8192 + b * 2048;

  const int srow = l >> 3;
  const int sj = (l & 7) ^ srow;
  const int krow = w * 8 + srow;
  const int klog = ((krow >> 5) << 5) | (((krow >> 2) & 3) << 3)
                 | (((krow >> 4) & 1) << 2) | (krow & 3);
  const int ldsoff = w * 1024;

  bf16x8 qfh[2][2], qfl[2][2];
#pragma unroll
  for (int nt = 0; nt < 2; ++nt)
#pragma unroll
    for (int kc = 0; kc < 2; ++kc) {
      const size_t off = (size_t)(q0 + w * 32 + nt * 16 + lr) * 2048 + kc * 32 + g * 8;
      qfh[nt][kc] = *(const bf16x8*)&Qh[off];
      qfl[nt][kc] = *(const bf16x8*)&Ql[off];
    }

  f32x4 zero = {0.f, 0.f, 0.f, 0.f};
  f32x4 o[2][4];
#pragma unroll
  for (int nt = 0; nt < 2; ++nt)
#pragma unroll
    for (int dn = 0; dn < 4; ++dn) o[nt][dn] = zero;
  float mst[2] = {-3.0e38f, -3.0e38f};
  float lst[2] = {0.f, 0.f};

  const float c1 = 0.125f * 1.44269504088896f;
  const float slope2 = -(float)(h + 1) * 1.44269504088896f;
  const float s2r1 = slope2, s2r2 = slope2 * 2.0f, s2r3 = slope2 * 3.0f;
  float base[4];
#pragma unroll
  for (int mt = 0; mt < 4; ++mt)
    base[mt] = slope2 * (float)(((mt >> 1) << 5) + ((mt & 1) << 2) + g * 8);
  const float bstep = slope2 * 64.0f;

  auto STAGE = [&](int tile, int buf) {
    GLL(Kh + (size_t)(tile * 64 + klog) * 2048 + sj * 8, (char*)&Ksh[buf][0] + ldsoff);
    GLL(Kl + (size_t)(tile * 64 + klog) * 2048 + sj * 8, (char*)&Ksl[buf][0] + ldsoff);
    GLL(Vb + (size_t)krow * 8192 + tile * 64 + sj * 8, (char*)&Vts[buf][0] + ldsoff);
  };

  auto QK = [&](int buf, f32x4 (&c)[4][2]) {
    const u16* Kcur = &Ksh[buf][0];
    const u16* Lcur = &Ksl[buf][0];
#pragma unroll
    for (int mt = 0; mt < 4; ++mt)
#pragma unroll
      for (int nt = 0; nt < 2; ++nt) c[mt][nt] = zero;
    __builtin_amdgcn_s_setprio(1);
#pragma unroll
    for (int mt = 0; mt < 4; ++mt) {
      bf16x8 ah[2], al[2];
#pragma unroll
      for (int kc = 0; kc < 2; ++kc) {
        const int rk = mt * 16 + lr;
        const int byte = rk * 128 + (((kc * 4 + g) ^ (rk & 7)) << 4);
        ah[kc] = *(const bf16x8*)((const char*)Kcur + byte);
        al[kc] = *(const bf16x8*)((const char*)Lcur + byte);
      }
#pragma unroll
      for (int nt = 0; nt < 2; ++nt) {
        f32x4 a = c[mt][nt];
        a = __builtin_amdgcn_mfma_f32_16x16x32_bf16(ah[0], qfh[nt][0], a, 0, 0, 0);
        a = __builtin_amdgcn_mfma_f32_16x16x32_bf16(ah[1], qfh[nt][1], a, 0, 0, 0);
        a = __builtin_amdgcn_mfma_f32_16x16x32_bf16(al[0], qfh[nt][0], a, 0, 0, 0);
        a = __builtin_amdgcn_mfma_f32_16x16x32_bf16(al[1], qfh[nt][1], a, 0, 0, 0);
        a = __builtin_amdgcn_mfma_f32_16x16x32_bf16(ah[0], qfl[nt][0], a, 0, 0, 0);
        a = __builtin_amdgcn_mfma_f32_16x16x32_bf16(ah[1], qfl[nt][1], a, 0, 0, 0);
        c[mt][nt] = a;
      }
    }
    __builtin_amdgcn_s_setprio(0);
  };

  auto SMPV = [&](f32x4 (&c)[4][2], int buf) {
    const u16* Vcur = &Vts[buf][0];
#pragma unroll
    for (int mt = 0; mt < 4; ++mt)
#pragma unroll
      for (int nt = 0; nt < 2; ++nt) {
        f32x4 a = c[mt][nt];
        a[0] = fmaf(a[0], c1, base[mt]);
        a[1] = fmaf(a[1], c1, base[mt] + s2r1);
        a[2] = fmaf(a[2], c1, base[mt] + s2r2);
        a[3] = fmaf(a[3], c1, base[mt] + s2r3);
        c[mt][nt] = a;
      }
    float rmax[2];
#pragma unroll
    for (int nt = 0; nt < 2; ++nt) {
      float m01 = fmaxf(fmaxf(c[0][nt][0], c[0][nt][1]), fmaxf(c[0][nt][2], c[0][nt][3]));
      float m23 = fmaxf(fmaxf(c[1][nt][0], c[1][nt][1]), fmaxf(c[1][nt][2], c[1][nt][3]));
      float m45 = fmaxf(fmaxf(c[2][nt][0], c[2][nt][1]), fmaxf(c[2][nt][2], c[2][nt][3]));
      float m67 = fmaxf(fmaxf(c[3][nt][0], c[3][nt][1]), fmaxf(c[3][nt][2], c[3][nt][3]));
      float m = fmaxf(fmaxf(m01, m23), fmaxf(m45, m67));
      m = fmaxf(m, __shfl_xor(m, 16));
      m = fmaxf(m, __shfl_xor(m, 32));
      rmax[nt] = m;
    }
    const bool needr = (rmax[0] > mst[0]) | (rmax[1] > mst[1]);
    if (__any(needr)) {
#pragma unroll
      for (int nt = 0; nt < 2; ++nt) {
        const float mn = fmaxf(mst[nt], rmax[nt]);
        const float alpha = EXP2F(mst[nt] - mn);
        mst[nt] = mn;
        lst[nt] *= alpha;
#pragma unroll
        for (int dn = 0; dn < 4; ++dn) {
          o[nt][dn][0] *= alpha; o[nt][dn][1] *= alpha;
          o[nt][dn][2] *= alpha; o[nt][dn][3] *= alpha;
        }
      }
    }
    bf16x8 pb[2][2];
#pragma unroll
    for (int nt = 0; nt < 2; ++nt) {
      float rsum = 0.f;
      uint32_t pk01[4], pk23[4];
#pragma unroll
      for (int mt = 0; mt < 4; ++mt) {
        const float p0 = EXP2F(c[mt][nt][0] - mst[nt]);
        const float p1 = EXP2F(c[mt][nt][1] - mst[nt]);
        const float p2 = EXP2F(c[mt][nt][2] - mst[nt]);
        const float p3 = EXP2F(c[mt][nt][3] - mst[nt]);
        rsum += (p0 + p1) + (p2 + p3);
        pk01[mt] = cvtpk_bf16(p0, p1);
        pk23[mt] = cvtpk_bf16(p2, p3);
      }
      rsum += __shfl_xor(rsum, 16);
      rsum += __shfl_xor(rsum, 32);
      lst[nt] += rsum;
      union { u32x4 u; bf16x8 bf; } cv0, cv1;
      cv0.u = (u32x4){pk01[0], pk23[0], pk01[1], pk23[1]};
      cv1.u = (u32x4){pk01[2], pk23[2], pk01[3], pk23[3]};
      pb[nt][0] = cv0.bf;
      pb[nt][1] = cv1.bf;
    }
    __builtin_amdgcn_s_setprio(1);
#pragma unroll
    for (int dn = 0; dn < 4; ++dn) {
      bf16x8 vb[2];
#pragma unroll
      for (int kc = 0; kc < 2; ++kc) {
        const int row = dn * 16 + lr;
        const int jk = kc * 4 + g;
        const int byte = row * 128 + ((jk ^ (row & 7)) << 4);
        vb[kc] = *(const bf16x8*)((const char*)Vcur + byte);
      }
#pragma unroll
      for (int nt = 0; nt < 2; ++nt) {
        o[nt][dn] = __builtin_amdgcn_mfma_f32_16x16x32_bf16(vb[0], pb[nt][0], o[nt][dn], 0, 0, 0);
        o[nt][dn] = __builtin_amdgcn_mfma_f32_16x16x32_bf16(vb[1], pb[nt][1], o[nt][dn], 0, 0, 0);
      }
    }
    __builtin_amdgcn_s_setprio(0);
#pragma unroll
    for (int mt = 0; mt < 4; ++mt) base[mt] += bstep;
  };

  STAGE(0, 0);
  __syncthreads();

  f32x4 cR[4][2];

  for (int kt = 0; kt < 32; ++kt) {
    if (kt + 1 < 32) STAGE(kt + 1, (kt + 1) % 3);
    if (w < 4) {
      QK(kt % 3, cR);
      SMPV(cR, kt % 3);
    } else {
      if (kt > 0) SMPV(cR, (kt + 2) % 3);
      QK(kt % 3, cR);
    }
    __syncthreads();
  }
  if (w >= 4) SMPV(cR, 31 % 3);

#pragma unroll
  for (int nt = 0; nt < 2; ++nt) {
    const float rinv = 1.0f / lst[nt];
    const int qrow = q0 + w * 32 + nt * 16 + lr;
#pragma unroll
    for (int dn = 0; dn < 4; ++dn) {
      uint2 pkv;
      pkv.x = cvtpk_bf16(o[nt][dn][0] * rinv, o[nt][dn][1] * rinv);
      pkv.y = cvtpk_bf16(o[nt][dn][2] * rinv, o[nt][dn][3] * rinv);
      *(uint2*)&multi[(rowbase + qrow) * 1024 + h * 64 + dn * 16 + g * 4] = pkv;
    }
  }
}

// ---------------- output GEMM + bias (swizzled LDS) ----------------
__global__ __launch_bounds__(256, 2) void out_gemm(
    const u16* __restrict__ A, const u16* __restrict__ Bw,
    const float* __restrict__ bias, float* __restrict__ out) {
  __shared__ u16 As[128 * 32], Bs[128 * 32];
  const int t = threadIdx.x, w = t >> 6, l = t & 63, g = l >> 4, lr = l & 15;
  const int m0 = blockIdx.y * 128, n0 = blockIdx.x * 128;
  const int wr = w >> 1, wc = w & 1;
  const int sk = (lr ^ (lr >> 2)) & 3;

  f32x4 zero = {0.f, 0.f, 0.f, 0.f};
  f32x4 acc[4][4];
#pragma unroll
  for (int mi = 0; mi < 4; ++mi)
#pragma unroll
    for (int ni = 0; ni < 4; ++ni) acc[mi][ni] = zero;

  for (int k0 = 0; k0 < 1024; k0 += 32) {
    __syncthreads();
#pragma unroll
    for (int i = 0; i < 2; ++i) {
      const int c = i * 256 + t;
      const int row = c >> 2;
      const int kc8 = ((c & 3) ^ (((c >> 2) ^ (c >> 4)) & 3)) * 8;
      const size_t goff = (size_t)row * 1024 + k0 + kc8;
      const int lo = i * 4096 + w * 1024;
      GLL(A + (size_t)m0 * 1024 + goff, (char*)As + lo);
      GLL(Bw + (size_t)n0 * 1024 + goff, (char*)Bs + lo);
    }
    __syncthreads();

    bf16x8 ah[4];
#pragma unroll
    for (int mi = 0; mi < 4; ++mi)
      ah[mi] = *(const bf16x8*)&As[(wr * 64 + mi * 16 + lr) * 32 + ((g ^ sk) << 3)];
#pragma unroll
    for (int ni = 0; ni < 4; ++ni) {
      bf16x8 bh = *(const bf16x8*)&Bs[(wc * 64 + ni * 16 + lr) * 32 + ((g ^ sk) << 3)];
#pragma unroll
      for (int mi = 0; mi < 4; ++mi)
        acc[mi][ni] = __builtin_amdgcn_mfma_f32_16x16x32_bf16(ah[mi], bh, acc[mi][ni], 0, 0, 0);
    }
  }

#pragma unroll
  for (int mi = 0; mi < 4; ++mi)
#pragma unroll
    for (int ni = 0; ni < 4; ++ni)
#pragma unroll
      for (int r = 0; r < 4; ++r) {
        const int row = m0 + wr * 64 + mi * 16 + g * 4 + r;
        const int col = n0 + wc * 64 + ni * 16 + lr;
        out[(size_t)row * 1024 + col] = acc[mi][ni][r] + bias[col];
      }
}

extern "C" void kernel_launch(void* const* d_in, const int* in_sizes, int n_in,
                              void* d_out, int out_size, void* d_ws, size_t ws_size,
                              hipStream_t stream) {
  (void)in_sizes; (void)n_in; (void)out_size; (void)ws_size;
  const float* x  = (const float*)d_in[0];
  const float* wq = (const float*)d_in[1];
  const float* wk = (const float*)d_in[2];
  const float* wv = (const float*)d_in[3];
  const float* wo = (const float*)d_in[4];
  const float* bo = (const float*)d_in[5];
  float* out = (float*)d_out;
  char* ws = (char*)d_ws;

  const size_t MB = 1024 * 1024;
  u16* xh   = (u16*)(ws + 0);        // 16 MB; reused as `multi` after qkv_gemm
  u16* xl   = (u16*)(ws + 16 * MB);  // 16 MB
  u16* qkh  = (u16*)(ws + 32 * MB);  // 32 MB
  u16* qkl  = (u16*)(ws + 64 * MB);  // 32 MB
  u16* vt   = (u16*)(ws + 96 * MB);  // 16 MB (V^T written directly by qkv_gemm)
  u16* wqkh = (u16*)(ws + 112 * MB); // 4 MB
  u16* wqkl = (u16*)(ws + 116 * MB); // 4 MB
  u16* wvb  = (u16*)(ws + 120 * MB); // 2 MB
  u16* wob  = (u16*)(ws + 122 * MB); // 2 MB
  u16* multi = xh;                   // x dead after qkv_gemm

  prep<<<12288, 256, 0, stream>>>(x, wq, wk, wv, wo, xh, xl, wqkh, wqkl, wvb, wob);
  qkv_gemm<<<dim3(12, 64), 256, 0, stream>>>(xh, xl, wqkh, wqkl, wvb, qkh, qkl, vt);
  attn<<<512, 512, 0, stream>>>(qkh, qkl, vt, multi);
  out_gemm<<<dim3(8, 64), 256, 0, stream>>>(multi, wob, bo, out);
}

// Round 14
// 313.351 us; speedup vs baseline: 1.0954x; 1.0954x over previous
//
#include <hip/hip_runtime.h>
#include <hip/hip_bf16.h>
#include <stdint.h>

typedef unsigned short u16;
typedef short bf16x8 __attribute__((ext_vector_type(8)));
typedef float f32x4 __attribute__((ext_vector_type(4)));
typedef uint32_t u32x4 __attribute__((ext_vector_type(4)));

#define DEV __device__ __forceinline__

DEV u16 f2bf(float f) {            // RNE (exact, for hi/lo splits)
  union { float f; uint32_t u; } v; v.f = f;
  uint32_t u = v.u;
  return (u16)((u + 0x7FFFu + ((u >> 16) & 1u)) >> 16);
}
DEV float bf2f(u16 h) {
  union { uint32_t u; float f; } v; v.u = ((uint32_t)h) << 16;
  return v.f;
}
DEV uint32_t cvtpk_bf16(float lo, float hi) {   // dst[15:0]=bf(lo), dst[31:16]=bf(hi)
  uint32_t r;
  asm volatile("v_cvt_pk_bf16_f32 %0, %1, %2" : "=v"(r) : "v"(lo), "v"(hi));
  return r;
}

#if __has_builtin(__builtin_amdgcn_exp2f)
#define EXP2F(x) __builtin_amdgcn_exp2f(x)
#else
#define EXP2F(x) exp2f(x)
#endif

#define GLL(gp, lp) __builtin_amdgcn_global_load_lds(\
    (const __attribute__((address_space(1))) unsigned int*)(gp), \
    (__attribute__((address_space(3))) unsigned int*)(lp), 16, 0, 0)

// ---------------- merged prep kernel ----------------
__global__ void prep(const float* __restrict__ x,
                     const float* __restrict__ wq, const float* __restrict__ wk,
                     const float* __restrict__ wv, const float* __restrict__ wo,
                     u16* __restrict__ xh, u16* __restrict__ xl,
                     u16* __restrict__ wqkh, u16* __restrict__ wqkl,
                     u16* __restrict__ wvb, u16* __restrict__ wob) {
  const int blk = blockIdx.x;
  if (blk < 8192) {
    int i = blk * 256 + threadIdx.x;
    float4 v = ((const float4*)x)[i];
    ushort4 h, lo;
    h.x = f2bf(v.x); h.y = f2bf(v.y); h.z = f2bf(v.z); h.w = f2bf(v.w);
    lo.x = f2bf(v.x - bf2f(h.x)); lo.y = f2bf(v.y - bf2f(h.y));
    lo.z = f2bf(v.z - bf2f(h.z)); lo.w = f2bf(v.w - bf2f(h.w));
    ((ushort4*)xh)[i] = h;
    ((ushort4*)xl)[i] = lo;
  } else {
    int i = (blk - 8192) * 256 + threadIdx.x;
    int seg = i >> 18;
    int j = i & ((1 << 18) - 1);
    const float* src = (seg == 0) ? wq : (seg == 1) ? wk : (seg == 2) ? wv : wo;
    float4 v = ((const float4*)src)[j];
    ushort4 h;
    h.x = f2bf(v.x); h.y = f2bf(v.y); h.z = f2bf(v.z); h.w = f2bf(v.w);
    if (seg < 2) {
      ushort4 lo;
      lo.x = f2bf(v.x - bf2f(h.x)); lo.y = f2bf(v.y - bf2f(h.y));
      lo.z = f2bf(v.z - bf2f(h.z)); lo.w = f2bf(v.w - bf2f(h.w));
      ((ushort4*)wqkh)[i] = h;
      ((ushort4*)wqkl)[i] = lo;
    } else if (seg == 2) {
      ((ushort4*)wvb)[j] = h;
    } else {
      ((ushort4*)wob)[j] = h;
    }
  }
}

// ---------------- fused QKV projection GEMM (round-12 form + XCD-chunked grid) ----------------
// 128x128 tile, 2-barrier, swizzled LDS, fused V-transpose epilogue.
// 1-D grid 1536, bijective XCD chunking: consecutive blocks in an XCD share A-tiles.
__global__ __launch_bounds__(256, 2) void qkv_gemm(
    const u16* __restrict__ xh, const u16* __restrict__ xl,
    const u16* __restrict__ wh, const u16* __restrict__ wl,
    const u16* __restrict__ wv,
    u16* __restrict__ qkh, u16* __restrict__ qkl, u16* __restrict__ vt) {
  __shared__ u16 LDS4[4][4096];   // [0]=Ah [1]=Bh [2]=Al [3]=Bl ; [2..3] doubles as V-transpose scratch
  const int t = threadIdx.x, w = t >> 6, l = t & 63, g = l >> 4, lr = l & 15;
  const int bid = blockIdx.x;
  const int swz = (bid & 7) * 192 + (bid >> 3);   // 1536 = 8 XCDs x 192
  const int bx = swz % 24, by = swz / 24;
  const int m0 = by * 128, n0 = bx * 128;
  const bool split = (n0 < 2048);
  const u16* bsrc_h = split ? (wh + (size_t)n0 * 1024) : (wv + (size_t)(n0 - 2048) * 1024);
  const u16* bsrc_l = split ? (wl + (size_t)n0 * 1024) : wl;
  const int wr = w >> 1, wc = w & 1;
  const int sk = (lr ^ (lr >> 2)) & 3;    // read-side swizzle key

  f32x4 zero = {0.f, 0.f, 0.f, 0.f};
  f32x4 acc[4][4];
#pragma unroll
  for (int mi = 0; mi < 4; ++mi)
#pragma unroll
    for (int ni = 0; ni < 4; ++ni) acc[mi][ni] = zero;

  for (int k0 = 0; k0 < 1024; k0 += 32) {
    __syncthreads();
#pragma unroll
    for (int i = 0; i < 2; ++i) {
      const int c = i * 256 + t;
      const int row = c >> 2;
      const int kc8 = ((c & 3) ^ (((c >> 2) ^ (c >> 4)) & 3)) * 8;
      const size_t goff = (size_t)row * 1024 + k0 + kc8;
      const int lo = i * 4096 + w * 1024;
      GLL(xh + (size_t)m0 * 1024 + goff, (char*)&LDS4[0][0] + lo);
      GLL(bsrc_h + goff, (char*)&LDS4[1][0] + lo);
      if (split) {
        GLL(xl + (size_t)m0 * 1024 + goff, (char*)&LDS4[2][0] + lo);
        GLL(bsrc_l + goff, (char*)&LDS4[3][0] + lo);
      }
    }
    __syncthreads();

    bf16x8 ah[4], al[4];
#pragma unroll
    for (int mi = 0; mi < 4; ++mi) {
      const int idx = (wr * 64 + mi * 16 + lr) * 32 + ((g ^ sk) << 3);
      ah[mi] = *(const bf16x8*)&LDS4[0][idx];
      if (split) al[mi] = *(const bf16x8*)&LDS4[2][idx];
    }
#pragma unroll
    for (int ni = 0; ni < 4; ++ni) {
      const int idx = (wc * 64 + ni * 16 + lr) * 32 + ((g ^ sk) << 3);
      bf16x8 bh = *(const bf16x8*)&LDS4[1][idx];
      bf16x8 bl;
      if (split) bl = *(const bf16x8*)&LDS4[3][idx];
#pragma unroll
      for (int mi = 0; mi < 4; ++mi) {
        acc[mi][ni] = __builtin_amdgcn_mfma_f32_16x16x32_bf16(ah[mi], bh, acc[mi][ni], 0, 0, 0);
        if (split) {
          acc[mi][ni] = __builtin_amdgcn_mfma_f32_16x16x32_bf16(al[mi], bh, acc[mi][ni], 0, 0, 0);
          acc[mi][ni] = __builtin_amdgcn_mfma_f32_16x16x32_bf16(ah[mi], bl, acc[mi][ni], 0, 0, 0);
        }
      }
    }
  }

  if (split) {
#pragma unroll
    for (int mi = 0; mi < 4; ++mi)
#pragma unroll
      for (int ni = 0; ni < 4; ++ni)
#pragma unroll
        for (int r = 0; r < 4; ++r) {
          const int row = m0 + wr * 64 + mi * 16 + g * 4 + r;
          const int col = wc * 64 + ni * 16 + lr;
          const float cval = acc[mi][ni][r];
          const u16 h = f2bf(cval);
          qkh[(size_t)row * 2048 + n0 + col] = h;
          qkl[(size_t)row * 2048 + n0 + col] = f2bf(cval - bf2f(h));
        }
  } else {
    // V-transpose epilogue: two wc-halves through 16 KB scratch T = LDS4[2..3]
    const int n0v = n0 - 2048;
    u16* T = &LDS4[2][0];
    for (int hh = 0; hh < 2; ++hh) {
      if (wc == hh) {
#pragma unroll
        for (int mi = 0; mi < 4; ++mi)
#pragma unroll
          for (int ni = 0; ni < 4; ++ni) {
            const int c = ni * 16 + lr;
            const int row0 = wr * 64 + mi * 16 + g * 4;
            const int sw = (c & 31) << 2;
            uint2 pk;
            pk.x = cvtpk_bf16(acc[mi][ni][0], acc[mi][ni][1]);
            pk.y = cvtpk_bf16(acc[mi][ni][2], acc[mi][ni][3]);
            *(uint2*)&T[c * 128 + (row0 ^ sw)] = pk;
          }
      }
      __syncthreads();
      {
        const int cb = t >> 4;
        const int sl = t & 15;
#pragma unroll
        for (int e = 0; e < 4; ++e) {
          const int c = cb + e * 16;
          const int sw = (c & 31) << 2;
          const int s = sl * 8;
          const int p0 = s ^ sw;
          const int p1 = p0 ^ 4;
          uint2 lo = *(const uint2*)&T[c * 128 + p0];
          uint2 hi = *(const uint2*)&T[c * 128 + p1];
          uint4 ov; ov.x = lo.x; ov.y = lo.y; ov.z = hi.x; ov.w = hi.y;
          *(uint4*)&vt[(size_t)(n0v + hh * 64 + c) * 8192 + m0 + s] = ov;
        }
      }
      __syncthreads();
    }
  }
}

// ---------------- flash attention with ALiBi (8 waves x 32q, 256 q/block) ----------------
// Frozen round-9/12 state.
__global__ __launch_bounds__(512, 2) void attn(
    const u16* __restrict__ qkh, const u16* __restrict__ qkl,
    const u16* __restrict__ vt, u16* __restrict__ multi) {
  __shared__ u16 Ksh[3][4096], Ksl[3][4096], Vts[3][4096];
  const int t = threadIdx.x, w = t >> 6, l = t & 63, g = l >> 4, lr = l & 15;
  const int L = blockIdx.x;
  const int flat = (L & 7) * 64 + (L >> 3);
  const int b = flat >> 7, h = (flat >> 3) & 15, qt = flat & 7;
  const int q0 = qt * 256;
  const size_t rowbase = (size_t)b * 2048;
  const u16* Qh = qkh + rowbase * 2048 + h * 64;
  const u16* Ql = qkl + rowbase * 2048 + h * 64;
  const u16* Kh = qkh + rowbase * 2048 + 1024 + h * 64;
  const u16* Kl = qkl + rowbase * 2048 + 1024 + h * 64;
  const u16* Vb = vt + (size_t)(h * 64) * 8192 + b * 2048;

  const int srow = l >> 3;
  const int sj = (l & 7) ^ srow;
  const int krow = w * 8 + srow;
  const int klog = ((krow >> 5) << 5) | (((krow >> 2) & 3) << 3)
                 | (((krow >> 4) & 1) << 2) | (krow & 3);
  const int ldsoff = w * 1024;

  bf16x8 qfh[2][2], qfl[2][2];
#pragma unroll
  for (int nt = 0; nt < 2; ++nt)
#pragma unroll
    for (int kc = 0; kc < 2; ++kc) {
      const size_t off = (size_t)(q0 + w * 32 + nt * 16 + lr) * 2048 + kc * 32 + g * 8;
      qfh[nt][kc] = *(const bf16x8*)&Qh[off];
      qfl[nt][kc] = *(const bf16x8*)&Ql[off];
    }

  f32x4 zero = {0.f, 0.f, 0.f, 0.f};
  f32x4 o[2][4];
#pragma unroll
  for (int nt = 0; nt < 2; ++nt)
#pragma unroll
    for (int dn = 0; dn < 4; ++dn) o[nt][dn] = zero;
  float mst[2] = {-3.0e38f, -3.0e38f};
  float lst[2] = {0.f, 0.f};

  const float c1 = 0.125f * 1.44269504088896f;
  const float slope2 = -(float)(h + 1) * 1.44269504088896f;
  const float s2r1 = slope2, s2r2 = slope2 * 2.0f, s2r3 = slope2 * 3.0f;
  float base[4];
#pragma unroll
  for (int mt = 0; mt < 4; ++mt)
    base[mt] = slope2 * (float)(((mt >> 1) << 5) + ((mt & 1) << 2) + g * 8);
  const float bstep = slope2 * 64.0f;

  auto STAGE = [&](int tile, int buf) {
    GLL(Kh + (size_t)(tile * 64 + klog) * 2048 + sj * 8, (char*)&Ksh[buf][0] + ldsoff);
    GLL(Kl + (size_t)(tile * 64 + klog) * 2048 + sj * 8, (char*)&Ksl[buf][0] + ldsoff);
    GLL(Vb + (size_t)krow * 8192 + tile * 64 + sj * 8, (char*)&Vts[buf][0] + ldsoff);
  };

  auto QK = [&](int buf, f32x4 (&c)[4][2]) {
    const u16* Kcur = &Ksh[buf][0];
    const u16* Lcur = &Ksl[buf][0];
#pragma unroll
    for (int mt = 0; mt < 4; ++mt)
#pragma unroll
      for (int nt = 0; nt < 2; ++nt) c[mt][nt] = zero;
    __builtin_amdgcn_s_setprio(1);
#pragma unroll
    for (int mt = 0; mt < 4; ++mt) {
      bf16x8 ah[2], al[2];
#pragma unroll
      for (int kc = 0; kc < 2; ++kc) {
        const int rk = mt * 16 + lr;
        const int byte = rk * 128 + (((kc * 4 + g) ^ (rk & 7)) << 4);
        ah[kc] = *(const bf16x8*)((const char*)Kcur + byte);
        al[kc] = *(const bf16x8*)((const char*)Lcur + byte);
      }
#pragma unroll
      for (int nt = 0; nt < 2; ++nt) {
        f32x4 a = c[mt][nt];
        a = __builtin_amdgcn_mfma_f32_16x16x32_bf16(ah[0], qfh[nt][0], a, 0, 0, 0);
        a = __builtin_amdgcn_mfma_f32_16x16x32_bf16(ah[1], qfh[nt][1], a, 0, 0, 0);
        a = __builtin_amdgcn_mfma_f32_16x16x32_bf16(al[0], qfh[nt][0], a, 0, 0, 0);
        a = __builtin_amdgcn_mfma_f32_16x16x32_bf16(al[1], qfh[nt][1], a, 0, 0, 0);
        a = __builtin_amdgcn_mfma_f32_16x16x32_bf16(ah[0], qfl[nt][0], a, 0, 0, 0);
        a = __builtin_amdgcn_mfma_f32_16x16x32_bf16(ah[1], qfl[nt][1], a, 0, 0, 0);
        c[mt][nt] = a;
      }
    }
    __builtin_amdgcn_s_setprio(0);
  };

  auto SMPV = [&](f32x4 (&c)[4][2], int buf) {
    const u16* Vcur = &Vts[buf][0];
#pragma unroll
    for (int mt = 0; mt < 4; ++mt)
#pragma unroll
      for (int nt = 0; nt < 2; ++nt) {
        f32x4 a = c[mt][nt];
        a[0] = fmaf(a[0], c1, base[mt]);
        a[1] = fmaf(a[1], c1, base[mt] + s2r1);
        a[2] = fmaf(a[2], c1, base[mt] + s2r2);
        a[3] = fmaf(a[3], c1, base[mt] + s2r3);
        c[mt][nt] = a;
      }
    float rmax[2];
#pragma unroll
    for (int nt = 0; nt < 2; ++nt) {
      float m01 = fmaxf(fmaxf(c[0][nt][0], c[0][nt][1]), fmaxf(c[0][nt][2], c[0][nt][3]));
      float m23 = fmaxf(fmaxf(c[1][nt][0], c[1][nt][1]), fmaxf(c[1][nt][2], c[1][nt][3]));
      float m45 = fmaxf(fmaxf(c[2][nt][0], c[2][nt][1]), fmaxf(c[2][nt][2], c[2][nt][3]));
      float m67 = fmaxf(fmaxf(c[3][nt][0], c[3][nt][1]), fmaxf(c[3][nt][2], c[3][nt][3]));
      float m = fmaxf(fmaxf(m01, m23), fmaxf(m45, m67));
      m = fmaxf(m, __shfl_xor(m, 16));
      m = fmaxf(m, __shfl_xor(m, 32));
      rmax[nt] = m;
    }
    const bool needr = (rmax[0] > mst[0]) | (rmax[1] > mst[1]);
    if (__any(needr)) {
#pragma unroll
      for (int nt = 0; nt < 2; ++nt) {
        const float mn = fmaxf(mst[nt], rmax[nt]);
        const float alpha = EXP2F(mst[nt] - mn);
        mst[nt] = mn;
        lst[nt] *= alpha;
#pragma unroll
        for (int dn = 0; dn < 4; ++dn) {
          o[nt][dn][0] *= alpha; o[nt][dn][1] *= alpha;
          o[nt][dn][2] *= alpha; o[nt][dn][3] *= alpha;
        }
      }
    }
    bf16x8 pb[2][2];
#pragma unroll
    for (int nt = 0; nt < 2; ++nt) {
      float rsum = 0.f;
      uint32_t pk01[4], pk23[4];
#pragma unroll
      for (int mt = 0; mt < 4; ++mt) {
        const float p0 = EXP2F(c[mt][nt][0] - mst[nt]);
        const float p1 = EXP2F(c[mt][nt][1] - mst[nt]);
        const float p2 = EXP2F(c[mt][nt][2] - mst[nt]);
        const float p3 = EXP2F(c[mt][nt][3] - mst[nt]);
        rsum += (p0 + p1) + (p2 + p3);
        pk01[mt] = cvtpk_bf16(p0, p1);
        pk23[mt] = cvtpk_bf16(p2, p3);
      }
      rsum += __shfl_xor(rsum, 16);
      rsum += __shfl_xor(rsum, 32);
      lst[nt] += rsum;
      union { u32x4 u; bf16x8 bf; } cv0, cv1;
      cv0.u = (u32x4){pk01[0], pk23[0], pk01[1], pk23[1]};
      cv1.u = (u32x4){pk01[2], pk23[2], pk01[3], pk23[3]};
      pb[nt][0] = cv0.bf;
      pb[nt][1] = cv1.bf;
    }
    __builtin_amdgcn_s_setprio(1);
#pragma unroll
    for (int dn = 0; dn < 4; ++dn) {
      bf16x8 vb[2];
#pragma unroll
      for (int kc = 0; kc < 2; ++kc) {
        const int row = dn * 16 + lr;
        const int jk = kc * 4 + g;
        const int byte = row * 128 + ((jk ^ (row & 7)) << 4);
        vb[kc] = *(const bf16x8*)((const char*)Vcur + byte);
      }
#pragma unroll
      for (int nt = 0; nt < 2; ++nt) {
        o[nt][dn] = __builtin_amdgcn_mfma_f32_16x16x32_bf16(vb[0], pb[nt][0], o[nt][dn], 0, 0, 0);
        o[nt][dn] = __builtin_amdgcn_mfma_f32_16x16x32_bf16(vb[1], pb[nt][1], o[nt][dn], 0, 0, 0);
      }
    }
    __builtin_amdgcn_s_setprio(0);
#pragma unroll
    for (int mt = 0; mt < 4; ++mt) base[mt] += bstep;
  };

  STAGE(0, 0);
  __syncthreads();

  f32x4 cR[4][2];

  for (int kt = 0; kt < 32; ++kt) {
    if (kt + 1 < 32) STAGE(kt + 1, (kt + 1) % 3);
    if (w < 4) {
      QK(kt % 3, cR);
      SMPV(cR, kt % 3);
    } else {
      if (kt > 0) SMPV(cR, (kt + 2) % 3);
      QK(kt % 3, cR);
    }
    __syncthreads();
  }
  if (w >= 4) SMPV(cR, 31 % 3);

#pragma unroll
  for (int nt = 0; nt < 2; ++nt) {
    const float rinv = 1.0f / lst[nt];
    const int qrow = q0 + w * 32 + nt * 16 + lr;
#pragma unroll
    for (int dn = 0; dn < 4; ++dn) {
      uint2 pkv;
      pkv.x = cvtpk_bf16(o[nt][dn][0] * rinv, o[nt][dn][1] * rinv);
      pkv.y = cvtpk_bf16(o[nt][dn][2] * rinv, o[nt][dn][3] * rinv);
      *(uint2*)&multi[(rowbase + qrow) * 1024 + h * 64 + dn * 16 + g * 4] = pkv;
    }
  }
}

// ---------------- output GEMM + bias (swizzled LDS + XCD-chunked grid) ----------------
__global__ __launch_bounds__(256, 2) void out_gemm(
    const u16* __restrict__ A, const u16* __restrict__ Bw,
    const float* __restrict__ bias, float* __restrict__ out) {
  __shared__ u16 As[128 * 32], Bs[128 * 32];
  const int t = threadIdx.x, w = t >> 6, l = t & 63, g = l >> 4, lr = l & 15;
  const int bid = blockIdx.x;
  const int swz = (bid & 7) * 64 + (bid >> 3);    // 512 = 8 XCDs x 64
  const int m0 = (swz / 8) * 128, n0 = (swz % 8) * 128;
  const int wr = w >> 1, wc = w & 1;
  const int sk = (lr ^ (lr >> 2)) & 3;

  f32x4 zero = {0.f, 0.f, 0.f, 0.f};
  f32x4 acc[4][4];
#pragma unroll
  for (int mi = 0; mi < 4; ++mi)
#pragma unroll
    for (int ni = 0; ni < 4; ++ni) acc[mi][ni] = zero;

  for (int k0 = 0; k0 < 1024; k0 += 32) {
    __syncthreads();
#pragma unroll
    for (int i = 0; i < 2; ++i) {
      const int c = i * 256 + t;
      const int row = c >> 2;
      const int kc8 = ((c & 3) ^ (((c >> 2) ^ (c >> 4)) & 3)) * 8;
      const size_t goff = (size_t)row * 1024 + k0 + kc8;
      const int lo = i * 4096 + w * 1024;
      GLL(A + (size_t)m0 * 1024 + goff, (char*)As + lo);
      GLL(Bw + (size_t)n0 * 1024 + goff, (char*)Bs + lo);
    }
    __syncthreads();

    bf16x8 ah[4];
#pragma unroll
    for (int mi = 0; mi < 4; ++mi)
      ah[mi] = *(const bf16x8*)&As[(wr * 64 + mi * 16 + lr) * 32 + ((g ^ sk) << 3)];
#pragma unroll
    for (int ni = 0; ni < 4; ++ni) {
      bf16x8 bh = *(const bf16x8*)&Bs[(wc * 64 + ni * 16 + lr) * 32 + ((g ^ sk) << 3)];
#pragma unroll
      for (int mi = 0; mi < 4; ++mi)
        acc[mi][ni] = __builtin_amdgcn_mfma_f32_16x16x32_bf16(ah[mi], bh, acc[mi][ni], 0, 0, 0);
    }
  }

#pragma unroll
  for (int mi = 0; mi < 4; ++mi)
#pragma unroll
    for (int ni = 0; ni < 4; ++ni)
#pragma unroll
      for (int r = 0; r < 4; ++r) {
        const int row = m0 + wr * 64 + mi * 16 + g * 4 + r;
        const int col = n0 + wc * 64 + ni * 16 + lr;
        out[(size_t)row * 1024 + col] = acc[mi][ni][r] + bias[col];
      }
}

extern "C" void kernel_launch(void* const* d_in, const int* in_sizes, int n_in,
                              void* d_out, int out_size, void* d_ws, size_t ws_size,
                              hipStream_t stream) {
  (void)in_sizes; (void)n_in; (void)out_size; (void)ws_size;
  const float* x  = (const float*)d_in[0];
  const float* wq = (const float*)d_in[1];
  const float* wk = (const float*)d_in[2];
  const float* wv = (const float*)d_in[3];
  const float* wo = (const float*)d_in[4];
  const float* bo = (const float*)d_in[5];
  float* out = (float*)d_out;
  char* ws = (char*)d_ws;

  const size_t MB = 1024 * 1024;
  u16* xh   = (u16*)(ws + 0);        // 16 MB; reused as `multi` after qkv_gemm
  u16* xl   = (u16*)(ws + 16 * MB);  // 16 MB
  u16* qkh  = (u16*)(ws + 32 * MB);  // 32 MB
  u16* qkl  = (u16*)(ws + 64 * MB);  // 32 MB
  u16* vt   = (u16*)(ws + 96 * MB);  // 16 MB (V^T written directly by qkv_gemm)
  u16* wqkh = (u16*)(ws + 112 * MB); // 4 MB
  u16* wqkl = (u16*)(ws + 116 * MB); // 4 MB
  u16* wvb  = (u16*)(ws + 120 * MB); // 2 MB
  u16* wob  = (u16*)(ws + 122 * MB); // 2 MB
  u16* multi = xh;                   // x dead after qkv_gemm

  prep<<<12288, 256, 0, stream>>>(x, wq, wk, wv, wo, xh, xl, wqkh, wqkl, wvb, wob);
  qkv_gemm<<<1536, 256, 0, stream>>>(xh, xl, wqkh, wqkl, wvb, qkh, qkl, vt);
  attn<<<512, 512, 0, stream>>>(qkh, qkl, vt, multi);
  out_gemm<<<512, 256, 0, stream>>>(multi, wob, bo, out);
}